// Round 9
// baseline (96.122 us; speedup 1.0000x reference)
//
#include <hip/hip_runtime.h>

#define T_LEN 65536
#define C_CH 8
#define CLEN 16
#define NB 16
#define WIN (CLEN * NB)          // 256 steps per window
#define NBLK 1024                // 16 whi x 8 ch x 8 slot; 2 windows per wave
#define SCANW 6                  // 384 bits scanned per window
#define MAXB 32                  // step-block size

typedef short bf16x8 __attribute__((ext_vector_type(8)));
typedef float f32x4 __attribute__((ext_vector_type(4)));
typedef unsigned int uint;
typedef unsigned long long u64;

#define MFMA32 __builtin_amdgcn_mfma_f32_16x16x32_bf16

#define SC_RZ 1.4426950408889634f   // log2(e): folded into r/z rows
#define SC_N  2.8853900817779268f   // 2*log2(e): folded into n rows

__device__ __forceinline__ uint f2bf(float f) {           // RNE float->bf16
    uint u = __float_as_uint(f);
    return (u + 0x7FFFu + ((u >> 16) & 1u)) >> 16;
}
__device__ __forceinline__ uint pk(float a, float b) {
    return f2bf(a) | (f2bf(b) << 16);
}
__device__ __forceinline__ uint cvtpk(float lo, float hi) {
    uint r;
    asm("v_cvt_pk_bf16_f32 %0, %1, %2" : "=v"(r) : "v"(lo), "v"(hi));
    return r;
}
// 2^(-x) via builtin: compiler knows it's TRANS and handles the hazard
// (inline-asm v_exp_f32 was the R7 silent-corruption cause).
__device__ __forceinline__ float expneg(float x) {
    return __builtin_amdgcn_exp2f(-x);
}
__device__ __forceinline__ bf16x8 mk8(uint a, uint b, uint c, uint d) {
    union { uint u[4]; bf16x8 v; } x;
    x.u[0] = a; x.u[1] = b; x.u[2] = c; x.u[3] = d;
    return x.v;
}
__device__ __forceinline__ float rcpf(float v) { return __builtin_amdgcn_rcpf(v); }

__global__ __launch_bounds__(64, 1) void gru_mfma(
    const float* __restrict__ x,     // (T,10,8)
    const int*   __restrict__ cg,    // (T,8)
    const int*   __restrict__ cs,    // (T,8)
    const float* __restrict__ W_ih,  // (8,192,4)
    const float* __restrict__ W_hh,  // (8,192,64)
    const float* __restrict__ b_ih,  // (8,192)
    const float* __restrict__ b_hh,  // (8,192)
    const float* __restrict__ W_out, // (8,1,64)
    const float* __restrict__ b_out, // (8,)
    float* __restrict__ y)           // (T,)
{
    __shared__ u64 stw[2][SCANW], acw[2][SCANW];
    __shared__ int sb[2][NB + 1];
    __shared__ float yw[2][NB][MAXB + 1];
    __shared__ uint2 bxl[2][MAXB][NB];

    const int lane = threadIdx.x;
    const int l15 = lane & 15, l4 = lane >> 4;
    // decode: all 8 channels of one time-slot share an XCD (bid%8 = w%8);
    // one wave runs windows {wA, wA+128} of the SAME channel (shared weights).
    const int slot = blockIdx.x & 7;
    const int c    = (blockIdx.x >> 3) & 7;
    const int whi  = blockIdx.x >> 6;        // 0..15
    const int wA   = whi * 8 + slot;         // 0..127
    const int RBs[2] = { wA * WIN, (wA + 128) * WIN };

    // ---- cooperative scan of cs/cg bits, both windows ----
#pragma unroll
    for (int wi = 0; wi < 2; ++wi)
        for (int rr = 0; rr < SCANW; ++rr) {
            int t = RBs[wi] + rr * 64 + lane;
            int sv = 0, av = 0;
            if (t < T_LEN) { sv = cs[t * C_CH + c]; av = cg[t * C_CH + c]; }
            u64 m1 = __ballot(sv == 1);
            u64 m2 = __ballot(av == 1);
            if (lane == 0) { stw[wi][rr] = m1; acw[wi][rr] = m2; }
        }
    __syncthreads();

    // ---- start-aligned boundaries per window ----
#pragma unroll
    for (int wi = 0; wi < 2; ++wi) {
        if (lane <= NB) {
            int rel = lane * CLEN;
            int q = rel >> 6, r0 = rel & 63;
            u64 m = stw[wi][q] >> r0;
            int pos = -1;
            if (m) pos = rel + __ffsll(m) - 1;
            else {
                for (int q2 = q + 1; q2 < SCANW; ++q2)
                    if (stw[wi][q2]) { pos = (q2 << 6) + __ffsll(stw[wi][q2]) - 1; break; }
            }
            int Sa;
            if (pos >= 0) Sa = RBs[wi] + pos;
            else {  // ultra-rare fallback
                int t = RBs[wi] + SCANW * 64;
                while (t < T_LEN && cs[t * C_CH + c] != 1) ++t;
                Sa = t;
            }
            sb[wi][lane] = min(Sa, T_LEN);
        }
    }
    __syncthreads();

    int SD[2], lenD[2];
#pragma unroll
    for (int wi = 0; wi < 2; ++wi) {
        SD[wi] = sb[wi][l15];
        lenD[wi] = sb[wi][l15 + 1] - SD[wi];
    }
    int Lmax = max(lenD[0], lenD[1]);
#pragma unroll
    for (int o = 1; o < 16; o <<= 1) Lmax = max(Lmax, __shfl_xor(Lmax, o));

    // ---- A-fragments (shared by both windows), log2e pre-scaled ----
    const float* Wc = W_hh + c * 192 * 64;
    uint Ah[12][2][4];
#pragma unroll
    for (int tm = 0; tm < 12; ++tm) {
        const float sc = (tm < 8) ? SC_RZ : SC_N;
#pragma unroll
        for (int kt = 0; kt < 2; ++kt) {
            const float* p = Wc + (16 * tm + l15) * 64 + 32 * kt + 4 * l4;
            float4 a = *(const float4*)p;
            float4 b = *(const float4*)(p + 16);
            Ah[tm][kt][0] = pk(a.x * sc, a.y * sc);
            Ah[tm][kt][1] = pk(a.z * sc, a.w * sc);
            Ah[tm][kt][2] = pk(b.x * sc, b.y * sc);
            Ah[tm][kt][3] = pk(b.z * sc, b.w * sc);
        }
    }
    // W_ih cols (k=0..3) + ones-column bias at k=4: r/z merged b_ih+b_hh; n: b_ih
    uint Axd[12][2];
#pragma unroll
    for (int tm = 0; tm < 12; ++tm) {
        const float sc = (tm < 8) ? SC_RZ : SC_N;
        int row = 16 * tm + l15;
        uint d0 = 0, d1 = 0;
        if (l4 == 0) {
            float4 wi4 = *(const float4*)(W_ih + (c * 192 + row) * 4);
            d0 = pk(wi4.x * sc, wi4.y * sc);
            d1 = pk(wi4.z * sc, wi4.w * sc);
        } else if (l4 == 1) {
            float bias = (tm < 8) ? (b_ih[c * 192 + row] + b_hh[c * 192 + row]) * SC_RZ
                                  : b_ih[c * 192 + row] * SC_N;
            d0 = f2bf(bias);
        }
        Axd[tm][0] = d0; Axd[tm][1] = d1;
    }
    // n-gate b_hh as fp32 C-init (row = 4*l4+i, column-independent)
    f32x4 bhn4[4];
#pragma unroll
    for (int tn = 0; tn < 4; ++tn) {
        float4 v = *(const float4*)(b_hh + c * 192 + 128 + 16 * tn + 4 * l4);
        bhn4[tn] = (f32x4){v.x * SC_N, v.y * SC_N, v.z * SC_N, v.w * SC_N};
    }

    float wof[16];
#pragma unroll
    for (int tm = 0; tm < 4; ++tm) {
        float4 v = *(const float4*)(W_out + c * 64 + 16 * tm + 4 * l4);
        wof[4 * tm + 0] = v.x; wof[4 * tm + 1] = v.y;
        wof[4 * tm + 2] = v.z; wof[4 * tm + 3] = v.w;
    }
    const float bo = b_out[c];

    // ---- state (x2 windows): h fp32 (D-layout) + bf16 B-frags ----
    float h[2][16];
    uint B0[2][4], B1[2][4];
#pragma unroll
    for (int wi = 0; wi < 2; ++wi) {
#pragma unroll
        for (int i = 0; i < 16; ++i) h[wi][i] = 0.f;
#pragma unroll
        for (int i = 0; i < 4; ++i) { B0[wi][i] = 0u; B1[wi][i] = 0u; }
    }
    const uint bx_c0 = (l4 == 1) ? 0x00003F80u : 0u;  // bf16(1.0) at k=4
    const f32x4 z4 = {0.f, 0.f, 0.f, 0.f};

// 9 MFMAs for row-tile TM, both windows (independent of all ACTs this step)
#define ISSUE(TM, R, Z, GX, GH)                                                       \
    do {                                                                              \
        _Pragma("unroll")                                                             \
        for (int wi = 0; wi < 2; ++wi) {                                              \
            f32x4 t_;                                                                 \
            t_ = MFMA32(mk8(Axd[TM][0], Axd[TM][1], 0u, 0u), Bxv[wi], z4, 0, 0, 0);   \
            t_ = MFMA32(mk8(Ah[TM][0][0], Ah[TM][0][1], Ah[TM][0][2], Ah[TM][0][3]),  \
                        Bh0v[wi], t_, 0, 0, 0);                                       \
            t_ = MFMA32(mk8(Ah[TM][1][0], Ah[TM][1][1], Ah[TM][1][2], Ah[TM][1][3]),  \
                        Bh1v[wi], t_, 0, 0, 0);                                       \
            R[wi] = t_;                                                               \
            t_ = MFMA32(mk8(Axd[TM + 4][0], Axd[TM + 4][1], 0u, 0u), Bxv[wi], z4, 0, 0, 0); \
            t_ = MFMA32(mk8(Ah[TM + 4][0][0], Ah[TM + 4][0][1], Ah[TM + 4][0][2], Ah[TM + 4][0][3]), \
                        Bh0v[wi], t_, 0, 0, 0);                                       \
            t_ = MFMA32(mk8(Ah[TM + 4][1][0], Ah[TM + 4][1][1], Ah[TM + 4][1][2], Ah[TM + 4][1][3]), \
                        Bh1v[wi], t_, 0, 0, 0);                                       \
            Z[wi] = t_;                                                               \
            GX[wi] = MFMA32(mk8(Axd[TM + 8][0], Axd[TM + 8][1], 0u, 0u), Bxv[wi], z4, 0, 0, 0); \
            t_ = MFMA32(mk8(Ah[TM + 8][0][0], Ah[TM + 8][0][1], Ah[TM + 8][0][2], Ah[TM + 8][0][3]), \
                        Bh0v[wi], bhn4[TM], 0, 0, 0);                                 \
            t_ = MFMA32(mk8(Ah[TM + 8][1][0], Ah[TM + 8][1][1], Ah[TM + 8][1][2], Ah[TM + 8][1][3]), \
                        Bh1v[wi], t_, 0, 0, 0);                                       \
            GH[wi] = t_;                                                              \
        }                                                                             \
    } while (0)

// activation for row-tile TM, both windows (VALU/trans; overlaps next ISSUE)
#define ACT(TM, R, Z, GX, GH)                                                         \
    do {                                                                              \
        _Pragma("unroll")                                                             \
        for (int wi = 0; wi < 2; ++wi) {                                              \
            float hv0, hv1, hv2, hv3;                                                 \
            _Pragma("unroll")                                                         \
            for (int i = 0; i < 4; ++i) {                                             \
                float rr = rcpf(1.f + expneg(R[wi][i]));                              \
                float zz = rcpf(1.f + expneg(Z[wi][i]));                              \
                float np2 = fmaf(rr, GH[wi][i], GX[wi][i]);                           \
                float nn = fmaf(2.f, rcpf(1.f + expneg(np2)), -1.f);                  \
                float hh = fmaf(zz, h[wi][4 * TM + i] - nn, nn);                      \
                h[wi][4 * TM + i] = hh;                                               \
                if (i == 0) hv0 = hh; else if (i == 1) hv1 = hh;                      \
                else if (i == 2) hv2 = hh; else hv3 = hh;                             \
                yp[wi] = fmaf(wof[4 * TM + i], hh, yp[wi]);                           \
            }                                                                         \
            nB[wi][2 * TM]     = cvtpk(hv0, hv1);                                     \
            nB[wi][2 * TM + 1] = cvtpk(hv2, hv3);                                     \
        }                                                                             \
    } while (0)

    for (int s0 = 0; s0 < Lmax; s0 += MAXB) {
        const int Lb = min(MAXB, Lmax - s0);

        // stage Bx payloads for both windows (p&15 == l15 at stride 64)
        const int npair = Lb * NB;
#pragma unroll
        for (int wi = 0; wi < 2; ++wi)
            for (int p = lane; p < npair; p += 64) {
                int s = p >> 4;
                int t = min(SD[wi] + s0 + s, T_LEN - 1);
                const float* xp = x + (size_t)t * 80 + 8 + c;
                bxl[wi][s][l15] = make_uint2(pk(xp[0], xp[8]), pk(xp[16], xp[24]));
            }
        // per-lane reset masks (region-guarded)
        u64 msD[2];
#pragma unroll
        for (int wi = 0; wi < 2; ++wi) {
            int off = (SD[wi] - RBs[wi]) + s0;
            int q = off >> 6, r0 = off & 63;
            u64 w0s = (q < SCANW) ? stw[wi][q] : 0ull;
            u64 w1s = (q + 1 < SCANW) ? stw[wi][q + 1] : 0ull;
            msD[wi] = (w0s >> r0) | (r0 ? (w1s << (64 - r0)) : 0ull);
        }
        __syncthreads();

        for (int s = 0; s < Lb; ++s) {
            bf16x8 Bxv[2], Bh0v[2], Bh1v[2];
#pragma unroll
            for (int wi = 0; wi < 2; ++wi) {
                const bool rst = (msD[wi] >> s) & 1;
#pragma unroll
                for (int i = 0; i < 16; ++i) h[wi][i] = rst ? 0.f : h[wi][i];
#pragma unroll
                for (int i = 0; i < 4; ++i) {
                    B0[wi][i] = rst ? 0u : B0[wi][i];
                    B1[wi][i] = rst ? 0u : B1[wi][i];
                }
                uint2 bx = bxl[wi][s][l15];
                Bxv[wi]  = mk8((lane < 16) ? bx.x : bx_c0,
                               (lane < 16) ? bx.y : 0u, 0u, 0u);
                Bh0v[wi] = mk8(B0[wi][0], B0[wi][1], B0[wi][2], B0[wi][3]);
                Bh1v[wi] = mk8(B1[wi][0], B1[wi][1], B1[wi][2], B1[wi][3]);
            }

            float yp[2] = {0.f, 0.f};
            uint nB[2][8];
            f32x4 aR[2], aZ[2], aGX[2], aGH[2];
            f32x4 bR[2], bZ[2], bGX[2], bGH[2];

            // software pipeline: tile k+1's MFMAs issue over tile k's activation
            ISSUE(0, aR, aZ, aGX, aGH);
            ISSUE(1, bR, bZ, bGX, bGH);
            ACT(0, aR, aZ, aGX, aGH);
            ISSUE(2, aR, aZ, aGX, aGH);
            ACT(1, bR, bZ, bGX, bGH);
            ISSUE(3, bR, bZ, bGX, bGH);
            ACT(2, aR, aZ, aGX, aGH);
            ACT(3, bR, bZ, bGX, bGH);

#pragma unroll
            for (int wi = 0; wi < 2; ++wi) {
                // D-layout == B-layout: tiles 0,1 -> Bh0; 2,3 -> Bh1
                B0[wi][0] = nB[wi][0]; B0[wi][1] = nB[wi][1];
                B0[wi][2] = nB[wi][2]; B0[wi][3] = nB[wi][3];
                B1[wi][0] = nB[wi][4]; B1[wi][1] = nB[wi][5];
                B1[wi][2] = nB[wi][6]; B1[wi][3] = nB[wi][7];

                float t1 = yp[wi] + __shfl_xor(yp[wi], 16);
                float t2 = t1 + __shfl_xor(t1, 32);
                if (lane < 16 && (s0 + s) < lenD[wi]) yw[wi][lane][s] = t2;
            }
        }
        __syncthreads();

        // write back both windows: one coalesced atomic row per chunk
#pragma unroll
        for (int wi = 0; wi < 2; ++wi)
            for (int b = 0; b < NB; ++b) {
                int Sb = sb[wi][b];
                int lenb = sb[wi][b + 1] - Sb;
                int sg = s0 + lane;
                if (lane < Lb && sg < lenb) {
                    int offa = (Sb - RBs[wi]) + sg;
                    int qa = offa >> 6;
                    bool act;
                    if (qa < SCANW) act = (acw[wi][qa] >> (offa & 63)) & 1;
                    else            act = cg[(Sb + sg) * C_CH + c] == 1;  // rare
                    if (act) atomicAdd(&y[Sb + sg], yw[wi][b][lane] + bo);
                }
            }
        __syncthreads();
    }
#undef ISSUE
#undef ACT
}

extern "C" void kernel_launch(void* const* d_in, const int* in_sizes, int n_in,
                              void* d_out, int out_size, void* d_ws, size_t ws_size,
                              hipStream_t stream) {
    const float* x     = (const float*)d_in[0];
    const int*   cg    = (const int*)  d_in[1];
    const int*   cs    = (const int*)  d_in[2];
    const float* W_ih  = (const float*)d_in[3];
    const float* W_hh  = (const float*)d_in[4];
    const float* b_ih  = (const float*)d_in[5];
    const float* b_hh  = (const float*)d_in[6];
    const float* W_out = (const float*)d_in[7];
    const float* b_out = (const float*)d_in[8];
    float* y = (float*)d_out;

    hipMemsetAsync(y, 0, (size_t)out_size * sizeof(float), stream);
    gru_mfma<<<NBLK, 64, 0, stream>>>(x, cg, cs, W_ih, W_hh, b_ih, b_hh,
                                      W_out, b_out, y);
}

// Round 10
// 93.904 us; speedup vs baseline: 1.0236x; 1.0236x over previous
//
#include <hip/hip_runtime.h>

#define T_LEN 65536
#define C_CH 8
#define CLEN 16
#define NB 16
#define WIN (CLEN * NB)          // 256 steps per window
#define NBLK 2048                // 32 whi x 8 ch x 8 slot; 1 window per wave
#define SCANW 6                  // 384 bits scanned per window
#define MAXB 32                  // step-block size

typedef short bf16x8 __attribute__((ext_vector_type(8)));
typedef float f32x4 __attribute__((ext_vector_type(4)));
typedef unsigned int uint;
typedef unsigned long long u64;

#define MFMA32 __builtin_amdgcn_mfma_f32_16x16x32_bf16

#define SC_RZ 1.4426950408889634f   // log2(e): folded into r/z rows
#define SC_N  2.8853900817779268f   // 2*log2(e): folded into n rows

__device__ __forceinline__ uint f2bf(float f) {           // RNE float->bf16
    uint u = __float_as_uint(f);
    return (u + 0x7FFFu + ((u >> 16) & 1u)) >> 16;
}
__device__ __forceinline__ uint pk(float a, float b) {
    return f2bf(a) | (f2bf(b) << 16);
}
__device__ __forceinline__ uint cvtpk(float lo, float hi) {
    uint r;
    asm("v_cvt_pk_bf16_f32 %0, %1, %2" : "=v"(r) : "v"(lo), "v"(hi));
    return r;
}
// 2^(-x) via builtin: compiler knows it's TRANS and handles the hazard
// (inline-asm v_exp_f32 was the R7 silent-corruption cause).
__device__ __forceinline__ float expneg(float x) {
    return __builtin_amdgcn_exp2f(-x);
}
__device__ __forceinline__ bf16x8 mk8(uint a, uint b, uint c, uint d) {
    union { uint u[4]; bf16x8 v; } x;
    x.u[0] = a; x.u[1] = b; x.u[2] = c; x.u[3] = d;
    return x.v;
}
__device__ __forceinline__ float rcpf(float v) { return __builtin_amdgcn_rcpf(v); }

// (64,1): do NOT cap the allocator. Natural VGPR count (~150-190) lands in
// the (128,256] class -> hardware runs 2 waves/SIMD from the 2048-block grid
// with ZERO spills. (64,2) forced a 128-reg target and spilled 56 MB (R8).
__global__ __launch_bounds__(64, 1) void gru_mfma(
    const float* __restrict__ x,     // (T,10,8)
    const int*   __restrict__ cg,    // (T,8)
    const int*   __restrict__ cs,    // (T,8)
    const float* __restrict__ W_ih,  // (8,192,4)
    const float* __restrict__ W_hh,  // (8,192,64)
    const float* __restrict__ b_ih,  // (8,192)
    const float* __restrict__ b_hh,  // (8,192)
    const float* __restrict__ W_out, // (8,1,64)
    const float* __restrict__ b_out, // (8,)
    float* __restrict__ y)           // (T,)
{
    __shared__ u64 stw[SCANW], acw[SCANW];
    __shared__ int sb[NB + 1];
    __shared__ float yw[NB][MAXB + 1];
    __shared__ uint2 bxl[MAXB][NB];

    const int lane = threadIdx.x;
    const int l15 = lane & 15, l4 = lane >> 4;
    // decode: all 8 channels of one time-slot share an XCD (bid%8 = w%8)
    const int slot = blockIdx.x & 7;
    const int c    = (blockIdx.x >> 3) & 7;
    const int whi  = blockIdx.x >> 6;        // 0..31
    const int w    = whi * 8 + slot;         // window id 0..255
    const int RB   = w * WIN;

    // ---- cooperative scan of cs/cg bits ----
    for (int rr = 0; rr < SCANW; ++rr) {
        int t = RB + rr * 64 + lane;
        int sv = 0, av = 0;
        if (t < T_LEN) { sv = cs[t * C_CH + c]; av = cg[t * C_CH + c]; }
        u64 m1 = __ballot(sv == 1);
        u64 m2 = __ballot(av == 1);
        if (lane == 0) { stw[rr] = m1; acw[rr] = m2; }
    }
    __syncthreads();

    // ---- 17 start-aligned boundaries: sb[k] = first start >= RB + k*CLEN ----
    if (lane <= NB) {
        int rel = lane * CLEN;
        int q = rel >> 6, r0 = rel & 63;
        u64 m = stw[q] >> r0;
        int pos = -1;
        if (m) pos = rel + __ffsll(m) - 1;
        else {
            for (int q2 = q + 1; q2 < SCANW; ++q2)
                if (stw[q2]) { pos = (q2 << 6) + __ffsll(stw[q2]) - 1; break; }
        }
        int Sa;
        if (pos >= 0) Sa = RB + pos;
        else {  // ultra-rare fallback: serial scan past region
            int t = RB + SCANW * 64;
            while (t < T_LEN && cs[t * C_CH + c] != 1) ++t;
            Sa = t;
        }
        sb[lane] = min(Sa, T_LEN);
    }
    __syncthreads();

    const int S = sb[l15];
    const int len = sb[l15 + 1] - S;
    int Lmax = len;
#pragma unroll
    for (int o = 1; o < 16; o <<= 1) Lmax = max(Lmax, __shfl_xor(Lmax, o));

    // ---- A-fragments (window constants), log2e pre-scaled ----
    const float* Wc = W_hh + c * 192 * 64;
    uint Ah[12][2][4];
#pragma unroll
    for (int tm = 0; tm < 12; ++tm) {
        const float sc = (tm < 8) ? SC_RZ : SC_N;
#pragma unroll
        for (int kt = 0; kt < 2; ++kt) {
            const float* p = Wc + (16 * tm + l15) * 64 + 32 * kt + 4 * l4;
            float4 a = *(const float4*)p;
            float4 b = *(const float4*)(p + 16);
            Ah[tm][kt][0] = pk(a.x * sc, a.y * sc);
            Ah[tm][kt][1] = pk(a.z * sc, a.w * sc);
            Ah[tm][kt][2] = pk(b.x * sc, b.y * sc);
            Ah[tm][kt][3] = pk(b.z * sc, b.w * sc);
        }
    }
    // W_ih cols (k=0..3) + ones-column bias at k=4: r/z merged b_ih+b_hh; n: b_ih
    uint Axd[12][2];
#pragma unroll
    for (int tm = 0; tm < 12; ++tm) {
        const float sc = (tm < 8) ? SC_RZ : SC_N;
        int row = 16 * tm + l15;
        uint d0 = 0, d1 = 0;
        if (l4 == 0) {
            float4 wi4 = *(const float4*)(W_ih + (c * 192 + row) * 4);
            d0 = pk(wi4.x * sc, wi4.y * sc);
            d1 = pk(wi4.z * sc, wi4.w * sc);
        } else if (l4 == 1) {
            float bias = (tm < 8) ? (b_ih[c * 192 + row] + b_hh[c * 192 + row]) * SC_RZ
                                  : b_ih[c * 192 + row] * SC_N;
            d0 = f2bf(bias);
        }
        Axd[tm][0] = d0; Axd[tm][1] = d1;
    }
    // n-gate b_hh as fp32 C-init (row = 4*l4+i, column-independent)
    f32x4 bhn4[4];
#pragma unroll
    for (int tn = 0; tn < 4; ++tn) {
        float4 v = *(const float4*)(b_hh + c * 192 + 128 + 16 * tn + 4 * l4);
        bhn4[tn] = (f32x4){v.x * SC_N, v.y * SC_N, v.z * SC_N, v.w * SC_N};
    }

    float wof[16];
#pragma unroll
    for (int tm = 0; tm < 4; ++tm) {
        float4 v = *(const float4*)(W_out + c * 64 + 16 * tm + 4 * l4);
        wof[4 * tm + 0] = v.x; wof[4 * tm + 1] = v.y;
        wof[4 * tm + 2] = v.z; wof[4 * tm + 3] = v.w;
    }
    const float bo = b_out[c];

    // ---- state: h fp32 (D-layout) + bf16 B-frags (same lane mapping) ----
    float h[16];
    uint B0[4], B1[4];
#pragma unroll
    for (int i = 0; i < 16; ++i) h[i] = 0.f;
#pragma unroll
    for (int i = 0; i < 4; ++i) { B0[i] = 0u; B1[i] = 0u; }
    const uint bx_c0 = (l4 == 1) ? 0x00003F80u : 0u;  // bf16(1.0) at k=4
    const f32x4 z4 = {0.f, 0.f, 0.f, 0.f};

    for (int s0 = 0; s0 < Lmax; s0 += MAXB) {
        const int Lb = min(MAXB, Lmax - s0);

        // stage Bx payloads: bxl[s][b] = packed bf16 {x1..x4}(t = S_b+s0+s)
        const int npair = Lb * NB;
        for (int p = lane; p < npair; p += 64) {
            int s = p >> 4;
            int t = min(sb[p & 15] + s0 + s, T_LEN - 1);
            const float* xp = x + (size_t)t * 80 + 8 + c;
            bxl[s][p & 15] = make_uint2(pk(xp[0], xp[8]), pk(xp[16], xp[24]));
        }
        // per-lane reset mask for its column, this step-block
        int off = (S - RB) + s0;
        int q = off >> 6, r0 = off & 63;
        u64 w0s = (q < SCANW) ? stw[q] : 0ull;
        u64 w1s = (q + 1 < SCANW) ? stw[q + 1] : 0ull;
        u64 ms = (w0s >> r0) | (r0 ? (w1s << (64 - r0)) : 0ull);
        __syncthreads();

        for (int s = 0; s < Lb; ++s) {
            const bool rst = (ms >> s) & 1;
#pragma unroll
            for (int i = 0; i < 16; ++i) h[i] = rst ? 0.f : h[i];
#pragma unroll
            for (int i = 0; i < 4; ++i) {
                B0[i] = rst ? 0u : B0[i];
                B1[i] = rst ? 0u : B1[i];
            }

            uint2 bx = bxl[s][l15];
            const bf16x8 Bx  = mk8((lane < 16) ? bx.x : bx_c0,
                                   (lane < 16) ? bx.y : 0u, 0u, 0u);
            const bf16x8 Bh0 = mk8(B0[0], B0[1], B0[2], B0[3]);
            const bf16x8 Bh1 = mk8(B1[0], B1[1], B1[2], B1[3]);

            float yp = 0.f;
            uint nB[8];
#pragma unroll
            for (int tm = 0; tm < 4; ++tm) {
                f32x4 ar = MFMA32(mk8(Axd[tm][0], Axd[tm][1], 0u, 0u), Bx, z4, 0, 0, 0);
                ar = MFMA32(mk8(Ah[tm][0][0], Ah[tm][0][1], Ah[tm][0][2], Ah[tm][0][3]), Bh0, ar, 0, 0, 0);
                ar = MFMA32(mk8(Ah[tm][1][0], Ah[tm][1][1], Ah[tm][1][2], Ah[tm][1][3]), Bh1, ar, 0, 0, 0);
                const int tz = tm + 4;
                f32x4 az = MFMA32(mk8(Axd[tz][0], Axd[tz][1], 0u, 0u), Bx, z4, 0, 0, 0);
                az = MFMA32(mk8(Ah[tz][0][0], Ah[tz][0][1], Ah[tz][0][2], Ah[tz][0][3]), Bh0, az, 0, 0, 0);
                az = MFMA32(mk8(Ah[tz][1][0], Ah[tz][1][1], Ah[tz][1][2], Ah[tz][1][3]), Bh1, az, 0, 0, 0);
                const int tn = tm + 8;
                f32x4 gx = MFMA32(mk8(Axd[tn][0], Axd[tn][1], 0u, 0u), Bx, z4, 0, 0, 0);
                f32x4 gh = MFMA32(mk8(Ah[tn][0][0], Ah[tn][0][1], Ah[tn][0][2], Ah[tn][0][3]), Bh0, bhn4[tm], 0, 0, 0);
                gh = MFMA32(mk8(Ah[tn][1][0], Ah[tn][1][1], Ah[tn][1][2], Ah[tn][1][3]), Bh1, gh, 0, 0, 0);

                float hv[4];
#pragma unroll
                for (int i = 0; i < 4; ++i) {
                    // pre-activations arrive pre-scaled by log2e (r/z) / 2log2e (n)
                    float rr = rcpf(1.f + expneg(ar[i]));
                    float zz = rcpf(1.f + expneg(az[i]));
                    float np2 = fmaf(rr, gh[i], gx[i]);
                    float nn = fmaf(2.f, rcpf(1.f + expneg(np2)), -1.f);
                    float hh = fmaf(zz, h[4 * tm + i] - nn, nn);
                    h[4 * tm + i] = hh;
                    hv[i] = hh;
                    yp = fmaf(wof[4 * tm + i], hh, yp);
                }
                nB[2 * tm]     = cvtpk(hv[0], hv[1]);
                nB[2 * tm + 1] = cvtpk(hv[2], hv[3]);
            }
            // D-layout == B-layout: tiles 0,1 -> Bh0; 2,3 -> Bh1
            B0[0] = nB[0]; B0[1] = nB[1]; B0[2] = nB[2]; B0[3] = nB[3];
            B1[0] = nB[4]; B1[1] = nB[5]; B1[2] = nB[6]; B1[3] = nB[7];

            float t1 = yp + __shfl_xor(yp, 16);
            float t2 = t1 + __shfl_xor(t1, 32);
            if (lane < 16 && (s0 + s) < len) yw[lane][s] = t2;
        }
        __syncthreads();

        // write back: one coalesced atomic row per chunk (channels collide)
        for (int b = 0; b < NB; ++b) {
            int Sb = sb[b];
            int lenb = sb[b + 1] - Sb;
            int sg = s0 + lane;
            if (lane < Lb && sg < lenb) {
                int offa = (Sb - RB) + sg;
                int qa = offa >> 6;
                bool act;
                if (qa < SCANW) act = (acw[qa] >> (offa & 63)) & 1;
                else            act = cg[(Sb + sg) * C_CH + c] == 1;  // rare
                if (act) atomicAdd(&y[Sb + sg], yw[b][lane] + bo);
            }
        }
        __syncthreads();
    }
}

extern "C" void kernel_launch(void* const* d_in, const int* in_sizes, int n_in,
                              void* d_out, int out_size, void* d_ws, size_t ws_size,
                              hipStream_t stream) {
    const float* x     = (const float*)d_in[0];
    const int*   cg    = (const int*)  d_in[1];
    const int*   cs    = (const int*)  d_in[2];
    const float* W_ih  = (const float*)d_in[3];
    const float* W_hh  = (const float*)d_in[4];
    const float* b_ih  = (const float*)d_in[5];
    const float* b_hh  = (const float*)d_in[6];
    const float* W_out = (const float*)d_in[7];
    const float* b_out = (const float*)d_in[8];
    float* y = (float*)d_out;

    hipMemsetAsync(y, 0, (size_t)out_size * sizeof(float), stream);
    gru_mfma<<<NBLK, 64, 0, stream>>>(x, cg, cs, W_ih, W_hh, b_ih, b_hh,
                                      W_out, b_out, y);
}